// Round 11
// baseline (107.037 us; speedup 1.0000x reference)
//
#include <hip/hip_runtime.h>
#include <math.h>

#define N_CODES     1024
#define CODE_DIM    64
#define ROWS_TOTAL  131072
#define CAND_CAP    12
#define GMARGIN     1e-3f
#define BROWS       128                      // rows per block (2 waves x 64 dual-row)
#define THREADS     128
#define STAGE_CODES 128
#define STAGE_BYTES (STAGE_CODES * CODE_DIM * 2)   // 16384

typedef float  f32x16  __attribute__((ext_vector_type(16)));
typedef short  short8v __attribute__((ext_vector_type(8)));
typedef __attribute__((address_space(3))) unsigned       lds_u32;
typedef const __attribute__((address_space(1))) unsigned glb_u32;

// ---------- frozen bit-exact pieces (verified rounds 2-10) ----------
__device__ __forceinline__ float np_sumsq64_s(const float* a, int stride) {
#pragma clang fp contract(off)
    float r[8];
    #pragma unroll
    for (int j = 0; j < 8; ++j) r[j] = a[j * stride] * a[j * stride];
    #pragma unroll
    for (int t = 1; t < 8; ++t) {
        #pragma unroll
        for (int j = 0; j < 8; ++j) {
            const float v = a[(t * 8 + j) * stride];
            const float p = v * v;
            r[j] = r[j] + p;
        }
    }
    return ((r[0] + r[1]) + (r[2] + r[3])) + ((r[4] + r[5]) + (r[6] + r[7]));
}

// same tree, reading element c at rq[c ^ x] (XOR-swizzled LDS row copy, x in [0,64))
__device__ __forceinline__ float np_sumsq64_lds(const float* rq, int x) {
#pragma clang fp contract(off)
    float r[8];
    #pragma unroll
    for (int j = 0; j < 8; ++j) { const float v = rq[j ^ x]; r[j] = v * v; }
    #pragma unroll
    for (int t = 1; t < 8; ++t) {
        #pragma unroll
        for (int j = 0; j < 8; ++j) {
            const float v = rq[(t * 8 + j) ^ x];
            const float p = v * v;
            r[j] = r[j] + p;
        }
    }
    return ((r[0] + r[1]) + (r[2] + r[3])) + ((r[4] + r[5]) + (r[6] + r[7]));
}

__device__ __forceinline__ unsigned short bf16rne(float f) {
    unsigned int u = __float_as_uint(f);
    return (unsigned short)((u + 0x7FFFu + ((u >> 16) & 1u)) >> 16);
}

__device__ __forceinline__ f32x16 zero16() {
    f32x16 v;
    #pragma unroll
    for (int e = 0; e < 16; ++e) v[e] = 0.f;
    return v;
}

__device__ __forceinline__ float exact_dot_lds(const float* rq, int x,
                                               const float* __restrict__ cb, int k) {
    const float4* wr = (const float4*)(cb + (size_t)k * CODE_DIM);
    float G = 0.f;
    #pragma unroll
    for (int c4 = 0; c4 < 16; ++c4) {
        const float4 wv = wr[c4];
        G = __builtin_fmaf(rq[(c4 * 4 + 0) ^ x], wv.x, G);
        G = __builtin_fmaf(rq[(c4 * 4 + 1) ^ x], wv.y, G);
        G = __builtin_fmaf(rq[(c4 * 4 + 2) ^ x], wv.z, G);
        G = __builtin_fmaf(rq[(c4 * 4 + 3) ^ x], wv.w, G);
    }
    return G;
}

// ordered (T,k) key: smaller key == (smaller T, then smaller k)
__device__ __forceinline__ unsigned long long packTK(float T, int k) {
    unsigned u = __float_as_uint(T);
    unsigned m = (u & 0x80000000u) ? ~u : (u | 0x80000000u);
    return ((unsigned long long)m << 32) | (unsigned)k;
}

// ========== K0: prep — ||w||^2 (numpy tree) + bf16 pre-swizzled codebook ==========
__global__ __launch_bounds__(512) void vq_prep(const float* __restrict__ cb,
                                               unsigned short* __restrict__ cbbf,
                                               float* __restrict__ Csws) {
    const int sid = blockIdx.x * 512 + threadIdx.x;       // 0..8191 (16B slots)
    const float4* cb4 = (const float4*)cb;
    const float4 f0 = cb4[sid * 2 + 0];
    const float4 f1 = cb4[sid * 2 + 1];
    short8v h;
    h[0] = (short)bf16rne(f0.x); h[1] = (short)bf16rne(f0.y);
    h[2] = (short)bf16rne(f0.z); h[3] = (short)bf16rne(f0.w);
    h[4] = (short)bf16rne(f1.x); h[5] = (short)bf16rne(f1.y);
    h[6] = (short)bf16rne(f1.z); h[7] = (short)bf16rne(f1.w);
    const int code = sid >> 3, c8 = sid & 7;
    const int off = (code >> 7) * STAGE_BYTES +
                    (((code & 127) * 128 + c8 * 16) ^ ((code & 7) << 4));
    *(short8v*)((char*)cbbf + off) = h;
    if (sid < N_CODES) Csws[sid] = np_sumsq64_s(cb + sid * CODE_DIM, 1);
}

// ========== K1: FUSED dual-row screen + compacted rescore + gather ==========
// 128 threads = 2 waves x 64 rows (dual-row MFMA); grid 1024; LDS = 40960 (4/CU).
__global__ __launch_bounds__(THREADS, 2) void vq_fused(
    const float* __restrict__ vec, const unsigned short* __restrict__ cbbf,
    const float* __restrict__ cb, const float* __restrict__ Csws,
    float* __restrict__ out)
{
    __shared__ __align__(16) char pool[2 * STAGE_BYTES];      // cbuf (screen) / rows (tail)
    __shared__ int cnt[BROWS];                                // cnt (screen) / S (tail)
    __shared__ int ks[BROWS * CAND_CAP];                      // 6 KB
    __shared__ unsigned long long res[BROWS];                 // 1 KB
    __shared__ int taskOff[BROWS];                            // 512 B
    // total: 32768 + 512 + 6144 + 1024 + 512 = 40960

    const int tid = threadIdx.x;
    const int l   = tid & 63;
    const int w   = tid >> 6;          // wave 0..1
    const int col = l & 31;
    const int g8  = l >> 5;
    const int rowblk = blockIdx.x * BROWS;
    const int rbase  = rowblk + w * 64;

    // ---- A fragments, TWO row sets per wave (rows rbase+col, rbase+32+col) ----
    short8v a0[4], a1[4];
    {
        const int r0 = rbase + col;
        const int r1 = rbase + 32 + col;
        const float* xb0 = vec + (size_t)(r0 >> 12) * 262144 + (r0 & 4095);
        const float* xb1 = vec + (size_t)(r1 >> 12) * 262144 + (r1 & 4095);
        #pragma unroll
        for (int m = 0; m < 4; ++m) {
            #pragma unroll
            for (int j = 0; j < 8; ++j) {
                const int c = m * 16 + g8 * 8 + j;
                a0[m][j] = (short)bf16rne(xb0[(size_t)c * 4096]);
                a1[m][j] = (short)bf16rne(xb1[(size_t)c * 4096]);
            }
        }
    }
    asm volatile("s_waitcnt vmcnt(0)" ::: "memory");   // clean vmcnt book
    #pragma unroll
    for (int m = 0; m < 4; ++m) {                      // pin fragments
        int4 t0; __builtin_memcpy(&t0, &a0[m], 16);
        asm volatile("" : "+v"(t0.x), "+v"(t0.y), "+v"(t0.z), "+v"(t0.w));
        __builtin_memcpy(&a0[m], &t0, 16);
        int4 t1; __builtin_memcpy(&t1, &a1[m], 16);
        asm volatile("" : "+v"(t1.x), "+v"(t1.y), "+v"(t1.z), "+v"(t1.w));
        __builtin_memcpy(&a1[m], &t1, 16);
    }

    // ---- staging: 8 x global_load_lds_dwordx4 per thread per 16KB stage ----
    const char* gsrc = (const char*)cbbf;
    #define STAGE(stg, bufi)                                                        \
        do {                                                                        \
            _Pragma("unroll")                                                       \
            for (int i = 0; i < 8; ++i) {                                           \
                const char* g = gsrc + (stg) * STAGE_BYTES + i * 2048 + tid * 16;   \
                lds_u32* lb = (lds_u32*)(pool + (bufi) * STAGE_BYTES + i * 2048 + (w << 10)); \
                __builtin_amdgcn_global_load_lds((glb_u32*)g, lb, 16, 0, 0);        \
            }                                                                       \
        } while (0)

    // Um doubles as threshold after the s==7 transition (in-place)
    f32x16 Um0, Um1;
    #pragma unroll
    for (int e = 0; e < 16; ++e) { Um0[e] = -INFINITY; Um1[e] = -INFINITY; }

    STAGE(0, 0);
    for (int s = 0; s < 16; ++s) {                     // 2 phases x 8 stages
        const int cur = s & 1;
        if (s < 15) {
            STAGE((s + 1) & 7, cur ^ 1);
            asm volatile("s_waitcnt vmcnt(8)" ::: "memory");  // prev stage landed
        } else {
            asm volatile("s_waitcnt vmcnt(0)" ::: "memory");
        }
        __builtin_amdgcn_s_barrier();
        __builtin_amdgcn_sched_barrier(0);

        const char* base = pool + cur * STAGE_BYTES;
        const int ph = s >> 3;
        const int kbase = (s & 7) * STAGE_CODES;
        #pragma unroll
        for (int tt = 0; tt < 4; ++tt) {
            const int cl = tt * 32 + col;
            short8v bf[4];
            #pragma unroll
            for (int m = 0; m < 4; ++m) {
                const int off = (cl * 128 + (m * 2 + g8) * 16) ^ ((cl & 7) << 4);
                bf[m] = *(const short8v*)(base + off);
            }
            f32x16 acc0 = zero16(), acc1 = zero16();
            #pragma unroll
            for (int m = 0; m < 4; ++m) {              // two independent chains (ILP)
                acc0 = __builtin_amdgcn_mfma_f32_32x32x16_bf16(a0[m], bf[m], acc0, 0, 0, 0);
                acc1 = __builtin_amdgcn_mfma_f32_32x32x16_bf16(a1[m], bf[m], acc1, 0, 0, 0);
            }

            if (ph == 0) {
                #pragma unroll
                for (int e = 0; e < 16; ++e) Um0[e] = fmaxf(Um0[e], acc0[e]);
                #pragma unroll
                for (int e = 0; e < 16; ++e) Um1[e] = fmaxf(Um1[e], acc1[e]);
            } else {
                const int k = kbase + cl;
                #pragma unroll
                for (int e = 0; e < 16; ++e) {
                    if (acc0[e] >= Um0[e]) {
                        const int rl = w * 64 + (e & 3) + ((e >> 2) << 3) + (g8 << 2);
                        const int idx = atomicAdd(&cnt[rl], 1);
                        if (idx < CAND_CAP) ks[rl * CAND_CAP + idx] = k;
                    }
                    if (acc1[e] >= Um1[e]) {
                        const int rl = w * 64 + 32 + (e & 3) + ((e >> 2) << 3) + (g8 << 2);
                        const int idx = atomicAdd(&cnt[rl], 1);
                        if (idx < CAND_CAP) ks[rl * CAND_CAP + idx] = k;
                    }
                }
            }
        }

        if (s == 7) {   // transition: butterfly max -> in-place thresholds; zero cnt
            #pragma unroll
            for (int e = 0; e < 16; ++e) {
                float v0 = Um0[e], v1 = Um1[e];
                v0 = fmaxf(v0, __shfl_xor(v0, 1, 64));  v1 = fmaxf(v1, __shfl_xor(v1, 1, 64));
                v0 = fmaxf(v0, __shfl_xor(v0, 2, 64));  v1 = fmaxf(v1, __shfl_xor(v1, 2, 64));
                v0 = fmaxf(v0, __shfl_xor(v0, 4, 64));  v1 = fmaxf(v1, __shfl_xor(v1, 4, 64));
                v0 = fmaxf(v0, __shfl_xor(v0, 8, 64));  v1 = fmaxf(v1, __shfl_xor(v1, 8, 64));
                v0 = fmaxf(v0, __shfl_xor(v0, 16, 64)); v1 = fmaxf(v1, __shfl_xor(v1, 16, 64));
                Um0[e] = v0 - GMARGIN;
                Um1[e] = v1 - GMARGIN;
            }
            cnt[w * 64 + l] = 0;                       // 64 wave-local rows
        }
        __builtin_amdgcn_s_barrier();
    }
    #undef STAGE

    // ================= tail: compacted exact rescore (64 rows/wave, 1:1 lanes) =====
    __syncthreads();                                   // all waves done with pool

    float (*rows)[CODE_DIM] = (float (*)[CODE_DIM])(pool + (size_t)w * STAGE_BYTES);
    float* Sarr = (float*)cnt;                         // overlay after cnt consumed

    // read cnt; init res; direct winners; overflow mask; task counts (all 64 lanes)
    const int c0 = cnt[w * 64 + l];
    res[w * 64 + l] = (c0 == 1)
        ? (unsigned long long)(unsigned)ks[(w * 64 + l) * CAND_CAP] : ~0ULL;
    const unsigned long long om0 = __ballot(c0 > CAND_CAP);
    const int tq = (c0 >= 2 && c0 <= CAND_CAP) ? c0 : 0;

    // exclusive prefix over all 64 lanes
    int scan = tq;
    #pragma unroll
    for (int off = 1; off < 64; off <<= 1) {
        const int v = __shfl_up(scan, off, 64);
        if (l >= off) scan += v;
    }
    taskOff[w * 64 + l] = scan - tq;
    const int total = __shfl(scan, 63, 64);

    // stage this wave's 64 rows into pool (XOR swizzle: rows[q][c ^ q] = x[c])
    {
        const float* rb = vec + (size_t)((rbase + l) >> 12) * 262144 + ((rbase + l) & 4095);
        #pragma unroll 8
        for (int c = 0; c < 64; ++c)
            rows[l][c ^ l] = rb[(size_t)c * 4096];     // coalesced across lanes per c
    }
    Sarr[w * 64 + l] = np_sumsq64_lds(rows[l], l);     // numpy tree, exact fp32 copies

    __builtin_amdgcn_s_barrier();                      // wave-local structures ready

    // ---- task loop: all 64 lanes, one (row,candidate) task per lane-round ----
    for (int t = l; t < total; t += 64) {
        int lo = 0, hi = 63;                           // largest q with taskOff<=t
        #pragma unroll
        for (int it = 0; it < 6; ++it) {
            const int mid = (lo + hi + 1) >> 1;
            if (taskOff[w * 64 + mid] <= t) lo = mid; else hi = mid - 1;
        }
        const int q = lo;
        const int k = ks[(w * 64 + q) * CAND_CAP + (t - taskOff[w * 64 + q])];
        const float S = Sarr[w * 64 + q];
        const float G = exact_dot_lds(rows[q], q, cb, k);
        const float T = __builtin_fmaf(-2.f, G, S) + Csws[k];
        atomicMin(&res[w * 64 + q], packTK(T, k));     // lexicographic (T,k)
    }

    // ---- rare overflow rows: wave-cooperative exact full scan (staged row) ----
    unsigned long long om = om0;
    while (om) {
        const int q = (int)__builtin_ctzll(om); om &= om - 1;
        const float S = Sarr[w * 64 + q];
        float bT = INFINITY; int bK = 0x7fffffff;
        #pragma unroll 4
        for (int j = 0; j < 16; ++j) {
            const int k = l * 16 + j;                  // ascending within lane
            const float G = exact_dot_lds(rows[q], q, cb, k);
            const float T = __builtin_fmaf(-2.f, G, S) + Csws[k];
            if (T < bT) { bT = T; bK = k; }
        }
        #pragma unroll
        for (int off = 32; off; off >>= 1) {           // lexicographic reduce
            const float oT = __shfl_xor(bT, off, 64);
            const int   oK = __shfl_xor(bK, off, 64);
            if (oT < bT || (oT == bT && oK < bK)) { bT = oT; bK = oK; }
        }
        if (l == 0) res[w * 64 + q] = (unsigned long long)(unsigned)bK;
    }

    __syncthreads();

    // ---- cooperative gather + coalesced float4 output write (128 rows) ----
    const int c4 = (tid & 15) << 2;
    for (int rr = tid >> 4; rr < BROWS; rr += 8) {
        const int wi = (int)(res[rr] & 0xffffffffu);
        const float4 v = *(const float4*)(cb + (size_t)wi * CODE_DIM + c4);
        *(float4*)(out + (size_t)(rowblk + rr) * CODE_DIM + c4) = v;
    }
}

// ================= fallback (round-4 kernel, used if ws too small) =================
#define KTILE 128
#define NTILES (N_CODES / KTILE)
__global__ __launch_bounds__(256, 2) void vq_lds_fallback(
    const float* __restrict__ vec, const float* __restrict__ cb,
    float* __restrict__ out)
{
    __shared__ __align__(16) float sw[2][KTILE * CODE_DIM];
    __shared__ __align__(16) float Cs[N_CODES];
    __shared__ int idxs[256];

    const int tid  = threadIdx.x;
    const int base = blockIdx.x * 256;
    const int b    = base >> 12;
    const int hw0  = base & 4095;

    #pragma unroll
    for (int j = 0; j < N_CODES / 256; ++j) {
        const int k = tid + j * 256;
        Cs[k] = np_sumsq64_s(cb + k * CODE_DIM, 1);
    }
    float xr[CODE_DIM];
    const float* xin = vec + (size_t)b * 262144 + hw0 + tid;
    #pragma unroll
    for (int c = 0; c < CODE_DIM; ++c) xr[c] = xin[(size_t)c * 4096];
    #pragma unroll
    for (int c = 0; c < CODE_DIM; ++c) asm volatile("" : "+v"(xr[c]));
    const float S = np_sumsq64_s(xr, 1);

    const float4* cb4 = (const float4*)cb;
    #pragma unroll
    for (int j = 0; j < 8; ++j)
        ((float4*)sw[0])[j * 256 + tid] = cb4[j * 256 + tid];
    __syncthreads();

    float m = INFINITY; int mi = 0;
    for (int t = 0; t < NTILES; ++t) {
        const int cur = t & 1;
        float4 g[8];
        if (t + 1 < NTILES) {
            #pragma unroll
            for (int j = 0; j < 8; ++j)
                g[j] = cb4[(size_t)(t + 1) * (KTILE * CODE_DIM / 4) + j * 256 + tid];
        }
        const float* wbase = sw[cur];
        for (int k0 = 0; k0 < KTILE; k0 += 4) {
            const float* w0 = wbase + (size_t)(k0 + 0) * CODE_DIM;
            const float* w1 = wbase + (size_t)(k0 + 1) * CODE_DIM;
            const float* w2 = wbase + (size_t)(k0 + 2) * CODE_DIM;
            const float* w3 = wbase + (size_t)(k0 + 3) * CODE_DIM;
            float d0 = 0.f, d1 = 0.f, d2 = 0.f, d3 = 0.f;
            #pragma unroll
            for (int c4 = 0; c4 < 16; ++c4) {
                const float4 a0 = *(const float4*)(w0 + c4 * 4);
                const float4 a1 = *(const float4*)(w1 + c4 * 4);
                const float4 a2 = *(const float4*)(w2 + c4 * 4);
                const float4 a3 = *(const float4*)(w3 + c4 * 4);
                d0 = __builtin_fmaf(xr[c4*4+0], a0.x, d0); d0 = __builtin_fmaf(xr[c4*4+1], a0.y, d0);
                d0 = __builtin_fmaf(xr[c4*4+2], a0.z, d0); d0 = __builtin_fmaf(xr[c4*4+3], a0.w, d0);
                d1 = __builtin_fmaf(xr[c4*4+0], a1.x, d1); d1 = __builtin_fmaf(xr[c4*4+1], a1.y, d1);
                d1 = __builtin_fmaf(xr[c4*4+2], a1.z, d1); d1 = __builtin_fmaf(xr[c4*4+3], a1.w, d1);
                d2 = __builtin_fmaf(xr[c4*4+0], a2.x, d2); d2 = __builtin_fmaf(xr[c4*4+1], a2.y, d2);
                d2 = __builtin_fmaf(xr[c4*4+2], a2.z, d2); d2 = __builtin_fmaf(xr[c4*4+3], a2.w, d2);
                d3 = __builtin_fmaf(xr[c4*4+0], a3.x, d3); d3 = __builtin_fmaf(xr[c4*4+1], a3.y, d3);
                d3 = __builtin_fmaf(xr[c4*4+2], a3.z, d3); d3 = __builtin_fmaf(xr[c4*4+3], a3.w, d3);
            }
            const int kg = t * KTILE + k0;
            const float4 cv = *(const float4*)&Cs[kg];
            const float t0 = __builtin_fmaf(-2.f, d0, S) + cv.x;
            const float t1 = __builtin_fmaf(-2.f, d1, S) + cv.y;
            const float t2 = __builtin_fmaf(-2.f, d2, S) + cv.z;
            const float t3 = __builtin_fmaf(-2.f, d3, S) + cv.w;
            if (t0 < m) { m = t0; mi = kg;     }
            if (t1 < m) { m = t1; mi = kg + 1; }
            if (t2 < m) { m = t2; mi = kg + 2; }
            if (t3 < m) { m = t3; mi = kg + 3; }
        }
        if (t + 1 < NTILES) {
            #pragma unroll
            for (int j = 0; j < 8; ++j)
                ((float4*)sw[cur ^ 1])[j * 256 + tid] = g[j];
        }
        __syncthreads();
    }
    idxs[tid] = mi;
    __syncthreads();
    const int c4 = (tid & 15) << 2;
    const int r0 = tid >> 4;
    for (int rr = r0; rr < 256; rr += 16) {
        const int wi = idxs[rr];
        const float4 v = *(const float4*)(cb + (size_t)wi * CODE_DIM + c4);
        *(float4*)(out + (size_t)(base + rr) * CODE_DIM + c4) = v;
    }
}

extern "C" void kernel_launch(void* const* d_in, const int* in_sizes, int n_in,
                              void* d_out, int out_size, void* d_ws, size_t ws_size,
                              hipStream_t stream) {
    const float* vec = (const float*)d_in[0];
    const float* cb  = (const float*)d_in[1];
    float* out = (float*)d_out;

    const size_t cbbf_b = (size_t)N_CODES * CODE_DIM * 2;
    const size_t cs_b   = (size_t)N_CODES * 4;
    const size_t need   = cbbf_b + cs_b;
    if (ws_size < need) {
        vq_lds_fallback<<<dim3(ROWS_TOTAL / 256), dim3(256), 0, stream>>>(vec, cb, out);
        return;
    }
    unsigned short* cbbf = (unsigned short*)d_ws;
    float* Csws = (float*)((char*)d_ws + cbbf_b);

    vq_prep<<<dim3(16), dim3(512), 0, stream>>>(cb, cbbf, Csws);
    vq_fused<<<dim3(ROWS_TOTAL / BROWS), dim3(THREADS), 0, stream>>>(vec, cbbf, cb, Csws, out);
}